// Round 11
// baseline (196.721 us; speedup 1.0000x reference)
//
#include <hip/hip_runtime.h>
#include <hip/hip_bf16.h>

// PhraseClassifier R11.
//   proj_gemm: 32-row M-tile, 34.8KB LDS -> 4 blocks/CU (R10 was 2: main
//     stall source). Barrier-free K-loop, blocked-B direct global->VGPR frags
//     (R10's fix), fp8 pair-layout output Wq[r] = [U[r] | V[r+32]].
//   span sort: counting sort by (bid, begin>>4) -> 1024 bins; hist/scan/
//     scatter, no global atomics; emits sorted int4 meta (oB, oE, flag, wt).
//     Consecutive span blocks then share a ~52KB Wq window -> L2 hits.
//   span_eval: R10 core, meta from sorted array (coalesced int4).

typedef float f32x4 __attribute__((ext_vector_type(4)));
typedef float f32x2 __attribute__((ext_vector_type(2)));
typedef __bf16 bf16x8 __attribute__((ext_vector_type(8)));

__device__ __forceinline__ unsigned short f2bf(float f) {
  unsigned int u = __float_as_uint(f);
  u += 0x7fffu + ((u >> 16) & 1u);   // RNE
  return (unsigned short)(u >> 16);
}
__device__ __forceinline__ float bf2f(unsigned int lo16) {
  return __uint_as_float(lo16 << 16);
}

// ---- prep: W1 [1024][512] fp32 -> W1b blocked [c=32][n=512][kk=32] bf16 ----
__global__ void w1_blocked(const float* __restrict__ W1,
                           unsigned short* __restrict__ W1b) {
  int idx = blockIdx.x * 256 + threadIdx.x;   // 0..65535
  int kc = idx & 3;
  int n  = (idx >> 2) & 511;
  int c  = idx >> 11;
  int k0 = c * 32 + kc * 8;
  unsigned short tmp[8];
#pragma unroll
  for (int j = 0; j < 8; ++j)
    tmp[j] = f2bf(W1[(k0 + j) * 512 + n]);
  *(uint4*)(W1b + c * 16384 + n * 32 + kc * 8) = *(uint4*)tmp;
}

// ---------------- sort: hist -> scan -> scatter (1024 bins, no glob atomics) ----
__global__ __launch_bounds__(256) void sort_hist(
    const int* __restrict__ bids, const int* __restrict__ begins,
    int* __restrict__ g) {                       // g: [32][1024]
  __shared__ int h[1024];
  const int t = threadIdx.x;
  for (int j = t; j < 1024; j += 256) h[j] = 0;
  __syncthreads();
  int base = blockIdx.x * 4096;
#pragma unroll 4
  for (int k = 0; k < 16; ++k) {
    int s = base + (k << 8) + t;
    int bin = (bids[s] << 5) | (begins[s] >> 4);
    atomicAdd(&h[bin], 1);
  }
  __syncthreads();
  for (int j = t; j < 1024; j += 256) g[blockIdx.x * 1024 + j] = h[j];
}

__global__ __launch_bounds__(256) void sort_scan(int* __restrict__ g) {
  __shared__ int wt[4];
  const int t = threadIdx.x, lane = t & 63, w = t >> 6;
  const int b0 = t << 2;                         // my 4 bins
  int tot0 = 0, tot1 = 0, tot2 = 0, tot3 = 0;
  for (int i = 0; i < 32; ++i) {
    int4 v = *(const int4*)(g + i * 1024 + b0);
    tot0 += v.x; tot1 += v.y; tot2 += v.z; tot3 += v.w;
  }
  int lsum = tot0 + tot1 + tot2 + tot3;
  int ts = lsum;
#pragma unroll
  for (int off = 1; off < 64; off <<= 1) {
    int n = __shfl_up(ts, off);
    if (lane >= off) ts += n;
  }
  if (lane == 63) wt[w] = ts;
  __syncthreads();
  int wbase = 0;
  for (int i = 0; i < w; ++i) wbase += wt[i];
  int r0 = wbase + ts - lsum;                    // exclusive base, bin b0
  int r1 = r0 + tot0, r2 = r1 + tot1, r3 = r2 + tot2;
  for (int i = 0; i < 32; ++i) {
    int4 v = *(const int4*)(g + i * 1024 + b0);
    *(int4*)(g + i * 1024 + b0) = make_int4(r0, r1, r2, r3);
    r0 += v.x; r1 += v.y; r2 += v.z; r3 += v.w;
  }
}

__global__ __launch_bounds__(256) void sort_scatter(
    const int* __restrict__ bids, const int* __restrict__ begins,
    const int* __restrict__ ends, const int* __restrict__ flags,
    const float* __restrict__ weights, const int* __restrict__ g,
    int4* __restrict__ smeta) {
  __shared__ int cur[1024];
  const int t = threadIdx.x;
  for (int j = t; j < 1024; j += 256) cur[j] = g[blockIdx.x * 1024 + j];
  __syncthreads();
  int base = blockIdx.x * 4096;
#pragma unroll 4
  for (int k = 0; k < 16; ++k) {
    int s = base + (k << 8) + t;
    int b = bids[s], bg = begins[s], en = ends[s];
    int bin = (b << 5) | (bg >> 4);
    int slot = atomicAdd(&cur[bin], 1);
    smeta[slot] = make_int4((((bg - 1) << 5) + b) << 10,
                            (((en - 1) << 5) + b) << 10,
                            flags[s], __float_as_int(weights[s]));
  }
}

// ---------------- proj_gemm: 32M x 512N per block, one K-half ----------------
// Grid (512, 2): x = M-tile (32 rows), y = half. Wave w owns cols [w*128,+128):
// acc 2m x 8n. A from LDS (contiguous staged); B frags direct global->VGPR
// from blocked W1b (1KB contiguous per frag load). 34.8KB LDS -> 4 blocks/CU.
#define APITCH 520
__global__ __launch_bounds__(256, 4) void proj_gemm(
    const float* __restrict__ hidden,        // [16384][1024]
    const unsigned short* __restrict__ w1b,  // blocked [32][512][32] bf16
    unsigned char* __restrict__ Wq) {        // [16384][1024] fp8: [U[r] | V[r+32]]
  __shared__ __align__(16) char smem[34816];           // max(AH 33280, Eb 34816)
  unsigned short* AH = (unsigned short*)smem;          // [32][520]
  unsigned short* Eb = (unsigned short*)smem;          // overlay [4][32][136]

  const int t = threadIdx.x;
  const int lane = t & 63;
  const int w = t >> 6;
  const int r0 = blockIdx.x << 5;
  const int hk = blockIdx.y << 9;            // 0 (U) or 512 (V)
  const int q = lane >> 4;                   // k-sub 0..3
  const int m = lane & 15;

  // ---- stage A: 32 rows x 512 cols fp32 -> bf16 LDS; thread = 64B contiguous
  {
    const int col = (t & 31) << 4;           // 0..496
    const int rsub = t >> 5;                 // 0..7
#pragma unroll
    for (int p = 0; p < 4; ++p) {
      int row = (p << 3) + rsub;             // 0..31
      const float4* gp = (const float4*)(hidden + ((r0 + row) << 10) + hk + col);
      float4 f0 = gp[0], f1 = gp[1], f2 = gp[2], f3 = gp[3];
      uint4 a, b;
      a.x = (unsigned)f2bf(f0.x) | ((unsigned)f2bf(f0.y) << 16);
      a.y = (unsigned)f2bf(f0.z) | ((unsigned)f2bf(f0.w) << 16);
      a.z = (unsigned)f2bf(f1.x) | ((unsigned)f2bf(f1.y) << 16);
      a.w = (unsigned)f2bf(f1.z) | ((unsigned)f2bf(f1.w) << 16);
      b.x = (unsigned)f2bf(f2.x) | ((unsigned)f2bf(f2.y) << 16);
      b.y = (unsigned)f2bf(f2.z) | ((unsigned)f2bf(f2.w) << 16);
      b.z = (unsigned)f2bf(f3.x) | ((unsigned)f2bf(f3.y) << 16);
      b.w = (unsigned)f2bf(f3.z) | ((unsigned)f2bf(f3.w) << 16);
      unsigned short* dst = AH + row * APITCH + col;
      *(uint4*)dst = a;
      *(uint4*)(dst + 8) = b;
    }
  }
  __syncthreads();

  int boffn[8];
#pragma unroll
  for (int nt = 0; nt < 8; ++nt)
    boffn[nt] = (((w << 7) + (nt << 4) + m) << 5) + (q << 3);
  const unsigned short* w1base = w1b + (blockIdx.y << 18);

  f32x4 acc[2][8];
#pragma unroll
  for (int i = 0; i < 2; ++i)
#pragma unroll
    for (int j = 0; j < 8; ++j) acc[i][j] = (f32x4){0.f, 0.f, 0.f, 0.f};

#pragma unroll
  for (int it = 0; it < 16; ++it) {
    const unsigned short* bt = w1base + (it << 14);
    bf16x8 bfr[8];
#pragma unroll
    for (int nt = 0; nt < 8; ++nt)
      bfr[nt] = *(const bf16x8*)(bt + boffn[nt]);
    bf16x8 af0 = *(const bf16x8*)(AH + m * APITCH + (it << 5) + (q << 3));
    bf16x8 af1 = *(const bf16x8*)(AH + (16 + m) * APITCH + (it << 5) + (q << 3));
#pragma unroll
    for (int nt = 0; nt < 8; ++nt) {
      acc[0][nt] = __builtin_amdgcn_mfma_f32_16x16x32_bf16(af0, bfr[nt], acc[0][nt], 0, 0, 0);
      acc[1][nt] = __builtin_amdgcn_mfma_f32_16x16x32_bf16(af1, bfr[nt], acc[1][nt], 0, 0, 0);
    }
  }
  __syncthreads();   // all waves done reading AH -> Eb may overlay it

  // ---- epilogue: wave-local repack + coalesced fp8 stores.
  // C/D layout: col = lane&15, row = (lane>>4)*4 + reg.
#pragma unroll
  for (int mt = 0; mt < 2; ++mt)
#pragma unroll
    for (int r = 0; r < 4; ++r) {
      int rr = (mt << 4) + ((lane >> 4) << 2) + r;   // 0..31
#pragma unroll
      for (int nt = 0; nt < 8; ++nt)
        Eb[((w << 5) + rr) * 136 + (nt << 4) + (lane & 15)] = f2bf(acc[mt][nt][r]);
    }
  // 32 rows x 128 cols per wave = 512 8-byte tasks
#pragma unroll
  for (int i = 0; i < 8; ++i) {
    int task = (i << 6) + lane;
    int rr = task >> 4;
    int ck = task & 15;
    uint4 v = *(const uint4*)&Eb[((w << 5) + rr) * 136 + (ck << 3)];
    float f0 = bf2f(v.x & 0xffff), f1 = bf2f(v.x >> 16);
    float f2 = bf2f(v.y & 0xffff), f3 = bf2f(v.y >> 16);
    float f4 = bf2f(v.z & 0xffff), f5 = bf2f(v.z >> 16);
    float f6 = bf2f(v.w & 0xffff), f7 = bf2f(v.w >> 16);
    uint2 o;
    o.x = __builtin_amdgcn_cvt_pk_fp8_f32(f0, f1, 0, false);
    o.x = __builtin_amdgcn_cvt_pk_fp8_f32(f2, f3, o.x, true);
    o.y = __builtin_amdgcn_cvt_pk_fp8_f32(f4, f5, 0, false);
    o.y = __builtin_amdgcn_cvt_pk_fp8_f32(f6, f7, o.y, true);
    int grow = r0 + rr;
    int col = (w << 7) + (ck << 3);
    if (hk == 0) {
      *(uint2*)(Wq + (grow << 10) + col) = o;              // U[r]
    } else if (grow >= 32) {
      *(uint2*)(Wq + ((grow - 32) << 10) + 512 + col) = o; // V[r] -> row r-32
    }
  }
}

// ---------------- span_eval: sorted meta, 1 span per half-wave ----------------
#define SPB 64
__global__ __launch_bounds__(256) void span_eval(
    const unsigned char* __restrict__ Wq, const int4* __restrict__ smeta,
    const float* __restrict__ b1, const float* __restrict__ w2,
    const float* __restrict__ b2, float* __restrict__ partials) {
  __shared__ int oB[SPB], oE[SPB], sfl[SPB];
  __shared__ float swt[SPB];
  __shared__ float red[4][3];
  const int t = threadIdx.x;
  const int lane = t & 63;
  const int w = t >> 6;
  const int h = lane >> 5;          // half-wave
  const int hl = lane & 31;
  const int sbase = blockIdx.x * SPB;

  if (t < SPB) {
    int4 mt = smeta[sbase + t];     // coalesced sorted meta
    oB[t] = mt.x;                   // row b-1: [U[b-1] | V[b]]
    oE[t] = mt.y;                   // row e-1: [U[e-1] | V[e]]
    sfl[t] = mt.z;
    swt[t] = __int_as_float(mt.w);
  }
  __syncthreads();

  const int sp0 = ((w << 1) + h) << 3;   // my half-wave's first span (block-local)
  const int c0 = hl << 4;                // 16 u-cols per lane
  float b1v[16], w2v[16];
#pragma unroll
  for (int qq = 0; qq < 4; ++qq) {
    float4 bv = *(const float4*)(b1 + c0 + (qq << 2));
    float4 wv = *(const float4*)(w2 + c0 + (qq << 2));
    b1v[(qq << 2) + 0] = bv.x; b1v[(qq << 2) + 1] = bv.y;
    b1v[(qq << 2) + 2] = bv.z; b1v[(qq << 2) + 3] = bv.w;
    w2v[(qq << 2) + 0] = wv.x; w2v[(qq << 2) + 1] = wv.y;
    w2v[(qq << 2) + 2] = wv.z; w2v[(qq << 2) + 3] = wv.w;
  }

  auto dec = [](unsigned int v, float* f) {
    f32x2 a = __builtin_amdgcn_cvt_pk_f32_fp8(v, false);
    f32x2 b = __builtin_amdgcn_cvt_pk_f32_fp8(v, true);
    f[0] = a[0]; f[1] = a[1]; f[2] = b[0]; f[3] = b[1];
  };

  uint4 BU[3], BV[3], EU[3], EV[3];
  auto ld = [&](int slot, int j) {
    int ob = oB[sp0 + j], oe = oE[sp0 + j];
    BU[slot] = *(const uint4*)(Wq + ob + c0);
    BV[slot] = *(const uint4*)(Wq + ob + 512 + c0);
    EU[slot] = *(const uint4*)(Wq + oe + c0);
    EV[slot] = *(const uint4*)(Wq + oe + 512 + c0);
  };
  ld(0, 0); ld(1, 1); ld(2, 2);

  float mylogit = 0.f;
#pragma unroll
  for (int j = 0; j < 8; ++j) {
    const int slot = j % 3;
    float buf[16], bvf[16], euf[16], evf[16];
    dec(BU[slot].x, buf); dec(BU[slot].y, buf + 4);
    dec(BU[slot].z, buf + 8); dec(BU[slot].w, buf + 12);
    dec(BV[slot].x, bvf); dec(BV[slot].y, bvf + 4);
    dec(BV[slot].z, bvf + 8); dec(BV[slot].w, bvf + 12);
    dec(EU[slot].x, euf); dec(EU[slot].y, euf + 4);
    dec(EU[slot].z, euf + 8); dec(EU[slot].w, euf + 12);
    dec(EV[slot].x, evf); dec(EV[slot].y, evf + 4);
    dec(EV[slot].z, evf + 8); dec(EV[slot].w, evf + 12);
    if (j + 3 < 8) ld(slot, j + 3);
    float sv = 0.f;
#pragma unroll
    for (int k = 0; k < 16; ++k) {
      float zp = euf[k] - buf[k] + bvf[k] - evf[k] + b1v[k];
      sv += fmaxf(zp, 0.f) * w2v[k];
    }
    sv += __shfl_xor(sv, 1);
    sv += __shfl_xor(sv, 2);
    sv += __shfl_xor(sv, 4);
    sv += __shfl_xor(sv, 8);
    sv += __shfl_xor(sv, 16);       // reduce within half-wave
    if (hl == j) mylogit = sv;      // lane h*32+j parks span sp0+j
  }

  mylogit = __shfl(mylogit, ((lane & 8) << 2) + (lane & 7));

  float pos_t = 0.f, neg_t = 0.f, cnt_t = 0.f;
  if (lane < 16) {
    int sl = (w << 4) + lane;
    float logit = mylogit + b2[0];
    float p = 1.f / (1.f + expf(-logit));
    p = fminf(fmaxf(p, 1e-7f), 1.f - 1e-7f);
    int fl = sfl[sl];
    float bce = (fl == 1) ? -logf(p) : -logf(1.f - p);
    float term = swt[sl] * bce;
    pos_t = (fl == 1) ? term : 0.f;
    neg_t = (fl == 1) ? 0.f : term;
    cnt_t = (fl == 1) ? 1.f : 0.f;
  }
#pragma unroll
  for (int off = 1; off < 64; off <<= 1) {
    pos_t += __shfl_xor(pos_t, off);
    neg_t += __shfl_xor(neg_t, off);
    cnt_t += __shfl_xor(cnt_t, off);
  }
  if (lane == 0) { red[w][0] = pos_t; red[w][1] = neg_t; red[w][2] = cnt_t; }
  __syncthreads();
  if (t == 0) {
    partials[(blockIdx.x << 2) + 0] = red[0][0] + red[1][0] + red[2][0] + red[3][0];
    partials[(blockIdx.x << 2) + 1] = red[0][1] + red[1][1] + red[2][1] + red[3][1];
    partials[(blockIdx.x << 2) + 2] = red[0][2] + red[1][2] + red[2][2] + red[3][2];
  }
}

// ---------------- finalize ----------------
__global__ void finalize(const float* __restrict__ parts, int nblk,
                         float* __restrict__ out, int nspans) {
  __shared__ float sp[4], sn[4], sc[4];
  float P = 0.f, Ng = 0.f, C = 0.f;
  for (int i = threadIdx.x; i < nblk; i += 256) {
    P += parts[(i << 2) + 0];
    Ng += parts[(i << 2) + 1];
    C += parts[(i << 2) + 2];
  }
#pragma unroll
  for (int off = 1; off < 64; off <<= 1) {
    P += __shfl_xor(P, off);
    Ng += __shfl_xor(Ng, off);
    C += __shfl_xor(C, off);
  }
  int w = threadIdx.x >> 6;
  if ((threadIdx.x & 63) == 0) { sp[w] = P; sn[w] = Ng; sc[w] = C; }
  __syncthreads();
  if (threadIdx.x == 0) {
    P = sp[0] + sp[1] + sp[2] + sp[3];
    Ng = sn[0] + sn[1] + sn[2] + sn[3];
    C = sc[0] + sc[1] + sc[2] + sc[3];
    float scale = 2.f * C / (float)nspans;
    out[0] = (P + scale * Ng) / (float)nspans;
  }
}

extern "C" void kernel_launch(void* const* d_in, const int* in_sizes, int n_in,
                              void* d_out, int out_size, void* d_ws, size_t ws_size,
                              hipStream_t stream) {
  const float* hidden = (const float*)d_in[0];
  const int* bids     = (const int*)d_in[1];
  const int* begins   = (const int*)d_in[2];
  const int* ends     = (const int*)d_in[3];
  const int* flags    = (const int*)d_in[4];
  const float* weights = (const float*)d_in[5];
  const float* W1 = (const float*)d_in[6];
  const float* b1 = (const float*)d_in[7];
  const float* W2 = (const float*)d_in[8];
  const float* b2 = (const float*)d_in[9];
  float* out = (float*)d_out;
  const int nspans = in_sizes[1];       // 131072
  const int nblk = nspans / SPB;        // 2048

  float* partials = (float*)d_ws;                                    // 32 KiB @0
  unsigned short* W1b = (unsigned short*)((char*)d_ws + (1 << 18));  // 1 MiB @256K
  int* ghist = (int*)((char*)d_ws + (3 << 19));                      // 128 KiB @1.5M
  unsigned char* Wq = (unsigned char*)((char*)d_ws + (2 << 20));     // 16.8 MiB @2M
  int4* smeta = (int4*)((char*)d_ws + (20 << 20));                   // 2 MiB @20M

  w1_blocked<<<256, 256, 0, stream>>>(W1, W1b);
  sort_hist<<<32, 256, 0, stream>>>(bids, begins, ghist);
  sort_scan<<<1, 256, 0, stream>>>(ghist);
  sort_scatter<<<32, 256, 0, stream>>>(bids, begins, ends, flags, weights,
                                       ghist, smeta);
  proj_gemm<<<dim3(512, 2), 256, 0, stream>>>(hidden, W1b, Wq);
  span_eval<<<nblk, 256, 0, stream>>>(Wq, smeta, b1, W2, b2, partials);
  finalize<<<1, 256, 0, stream>>>(partials, nblk, out, nspans);
}